// Round 9
// baseline (409.664 us; speedup 1.0000x reference)
//
#include <hip/hip_runtime.h>
#include <hip/hip_fp16.h>
#include <math.h>

#define HDIM 128
#define LN_EPS 1e-5f
#define NCOH 8  // XCD cohorts (blockIdx % 8 ~ XCD round-robin heuristic; perf-only)

typedef _Float16 half8 __attribute__((ext_vector_type(8)));
typedef float f32x4 __attribute__((ext_vector_type(4)));

// h'[v] = dinv[v]*h[v]; agg[v] = dinv[v]*(sum_{s in N(v)} h'[s] + h'[v]).
// CSR is cohort-sharded x-major: cohort x's edges for node v live at
// csr8[rowptr8[x*n+v] .. rowptr8[x*n+v+1]). No merge — consumers walk the 8
// segments directly (segment lengths are wave-uniform -> free branches).

// ---------------- CSR build ----------------

__global__ void count_kernel(const int* __restrict__ dst, int* __restrict__ counts8,
                             int E, int n) {
  int e = blockIdx.x * blockDim.x + threadIdx.x;
  int x = blockIdx.x & (NCOH - 1);
  if (e < E) atomicAdd(&counts8[x * n + dst[e]], 1);
}

__global__ void dinv_kernel(const int* __restrict__ counts8, float* __restrict__ dinv, int n) {
  int i = blockIdx.x * 256 + threadIdx.x;
  if (i < n) {
    int s = 0;
#pragma unroll
    for (int x = 0; x < NCOH; ++x) s += counts8[x * n + i];
    dinv[i] = rsqrtf((float)(s + 1));  // +1 self-loop
  }
}

// Hierarchical scan over the 8N cohort-sharded counts (256 threads, 8 elems/thread).
__global__ __launch_bounds__(256) void scan_sum_kernel(const int* __restrict__ in,
                                                       int* __restrict__ blocksum, int n) {
  int base = blockIdx.x * 2048;
  int tid = threadIdx.x;
  int sum = 0;
#pragma unroll
  for (int j = 0; j < 8; ++j) {
    int i = base + tid * 8 + j;
    if (i < n) sum += in[i];
  }
#pragma unroll
  for (int off = 32; off >= 1; off >>= 1) sum += __shfl_xor(sum, off, 64);
  __shared__ int wsum[4];
  if ((tid & 63) == 0) wsum[tid >> 6] = sum;
  __syncthreads();
  if (tid == 0) blocksum[blockIdx.x] = wsum[0] + wsum[1] + wsum[2] + wsum[3];
}

__global__ __launch_bounds__(256) void scan2_kernel(int* __restrict__ blocksum, int nblk) {
  __shared__ int sh[256];
  int tid = threadIdx.x;
  sh[tid] = (tid < nblk) ? blocksum[tid] : 0;
  __syncthreads();
  for (int off = 1; off < 256; off <<= 1) {
    int t = (tid >= off) ? sh[tid - off] : 0;
    __syncthreads();
    sh[tid] += t;
    __syncthreads();
  }
  if (tid < nblk) blocksum[tid] = sh[tid];  // inclusive
}

__global__ __launch_bounds__(256) void scan_emit_kernel(const int* __restrict__ in,
                                                        const int* __restrict__ blocksum,
                                                        int* __restrict__ rowptr8,
                                                        int* __restrict__ cursor8, int n, int nblk) {
  int base = blockIdx.x * 2048;
  int tid = threadIdx.x;
  int c[8];
  int s = 0;
#pragma unroll
  for (int j = 0; j < 8; ++j) {
    int i = base + tid * 8 + j;
    c[j] = (i < n) ? in[i] : 0;
    s += c[j];
  }
  int lane = tid & 63, wid = tid >> 6;
  int incl = s;
#pragma unroll
  for (int off = 1; off < 64; off <<= 1) {
    int t = __shfl_up(incl, off, 64);
    if (lane >= off) incl += t;
  }
  __shared__ int wsum[4];
  if (lane == 63) wsum[wid] = incl;
  __syncthreads();
  int woff = 0;
  for (int w = 0; w < wid; ++w) woff += wsum[w];
  int p = (blockIdx.x == 0 ? 0 : blocksum[blockIdx.x - 1]) + woff + (incl - s);
#pragma unroll
  for (int j = 0; j < 8; ++j) {
    int i = base + tid * 8 + j;
    if (i < n) {
      rowptr8[i] = p;
      cursor8[i] = p;
    }
    p += c[j];
  }
  if (blockIdx.x == nblk - 1 && tid == 255) rowptr8[n] = blocksum[nblk - 1];
}

__global__ void fill_kernel(const int* __restrict__ src, const int* __restrict__ dst,
                            int* __restrict__ cursor8, int* __restrict__ csr8, int E, int n) {
  int e = blockIdx.x * blockDim.x + threadIdx.x;
  int x = blockIdx.x & (NCOH - 1);
  if (e < E) {
    int pos = atomicAdd(&cursor8[x * n + dst[e]], 1);
    csr8[pos] = src[e];  // cohort-owned contiguous region -> XCD-local L2 lines
  }
}

// ---------------- Prep: x' = dinv*x ; fp16-transposed weights (fused) ----------------

__global__ void prep_kernel(const float* __restrict__ x, const float* __restrict__ dinv,
                            float* __restrict__ xs, const float* __restrict__ W2,
                            const float* __restrict__ W3, const float* __restrict__ rW1,
                            __half* __restrict__ w2t, __half* __restrict__ w3t,
                            __half* __restrict__ rw1t, int n) {
  int idx = blockIdx.x * 256 + threadIdx.x;
  int nx = n * 6;
  if (idx < nx) {
    xs[idx] = x[idx] * dinv[idx / 6];
    return;
  }
  int i = idx - nx;
  if (i < 16384) {
    int nn = i >> 7, k = i & 127;
    w2t[i] = __float2half(W2[k * 128 + nn]);
  } else if (i < 32768) {
    int j = i - 16384;
    int nn = j >> 7, k = j & 127;
    w3t[j] = __float2half(W3[k * 128 + nn]);
  } else if (i < 40960) {
    int j = i - 32768;
    int nn = j >> 7, k = j & 127;
    rw1t[j] = __float2half(rW1[k * 64 + nn]);
  }
}

// ---------------- Layer 1: one wave/node over 8 segments; 6->128 GEMM + LN + ReLU ----------

__global__ __launch_bounds__(256) void layer1_kernel(
    const float* __restrict__ xs, const float* __restrict__ W1,
    const float* __restrict__ b1, const float* __restrict__ gam,
    const float* __restrict__ bet, const int* __restrict__ rowptr8,
    const int* __restrict__ csr8, const float* __restrict__ dinv,
    __half* __restrict__ hout, int n) {
  int v = blockIdx.x * 4 + (threadIdx.x >> 6);
  if (v >= n) return;
  int lane = threadIdx.x & 63;
  int sx = 0, ex = 0;
  if (lane < NCOH) {
    sx = rowptr8[lane * n + v];
    ex = rowptr8[lane * n + v + 1];
  }
  int u = lane & 7;
  int su = __shfl(sx, u, 64);
  int lu = __shfl(ex, u, 64) - su;
  float a[6] = {0.f, 0.f, 0.f, 0.f, 0.f, 0.f};
  for (int i = lane >> 3; i < lu; i += 8) {
    int s = csr8[su + i];
#pragma unroll
    for (int j = 0; j < 6; ++j) a[j] += xs[s * 6 + j];
  }
  if (lane == 0) {
#pragma unroll
    for (int j = 0; j < 6; ++j) a[j] += xs[v * 6 + j];  // self-loop
  }
#pragma unroll
  for (int off = 32; off >= 1; off >>= 1) {
#pragma unroll
    for (int j = 0; j < 6; ++j) a[j] += __shfl_xor(a[j], off, 64);
  }
  float dv = dinv[v];
#pragma unroll
  for (int j = 0; j < 6; ++j) a[j] *= dv;
  int f0 = lane, f1 = lane + 64;
  float o0 = b1[f0], o1 = b1[f1];
#pragma unroll
  for (int j = 0; j < 6; ++j) {
    o0 = fmaf(a[j], W1[j * HDIM + f0], o0);
    o1 = fmaf(a[j], W1[j * HDIM + f1], o1);
  }
  float s = o0 + o1, q = o0 * o0 + o1 * o1;
#pragma unroll
  for (int off = 32; off >= 1; off >>= 1) {
    s += __shfl_xor(s, off, 64);
    q += __shfl_xor(q, off, 64);
  }
  float m = s * (1.0f / HDIM);
  float var = fmaxf(q * (1.0f / HDIM) - m * m, 0.f);
  float rs = rsqrtf(var + LN_EPS);
  float y0 = fmaxf(fmaf((o0 - m) * rs, gam[f0], bet[f0]), 0.f);
  float y1 = fmaxf(fmaf((o1 - m) * rs, gam[f1], bet[f1]), 0.f);
  hout[v * HDIM + f0] = __float2half(y0 * dv);  // store h' = dinv*h
  hout[v * HDIM + f1] = __float2half(y1 * dv);
}

// ---------------- Aggregation: one wave/node, 8 segments walked in lockstep --------------
// Per iteration: up to 8 independent row-gathers (one per segment). Segment lengths are
// wave-uniform -> `i < len[u]` is a free wave-level skip, no masked-load BW waste.

__global__ __launch_bounds__(256) void agg_kernel(
    const __half* __restrict__ hin, const int* __restrict__ rowptr8,
    const int* __restrict__ csr8, const float* __restrict__ dinv,
    __half* __restrict__ agg, int n) {
  int v = blockIdx.x * 4 + (threadIdx.x >> 6);
  if (v >= n) return;
  int lane = threadIdx.x & 63;
  const __half2* h2 = (const __half2*)hin;
  float2 hf = __half22float2(h2[v * 64 + lane]);
  float ax = hf.x, ay = hf.y;  // self-loop
  int sx = 0, ex = 0;
  if (lane < NCOH) {
    sx = rowptr8[lane * n + v];
    ex = rowptr8[lane * n + v + 1];
  }
  int start[NCOH], len[NCOH];
  int maxlen = 0;
#pragma unroll
  for (int u = 0; u < NCOH; ++u) {
    start[u] = __shfl(sx, u, 64);
    len[u] = __shfl(ex, u, 64) - start[u];
    maxlen = max(maxlen, len[u]);
  }
  for (int i = 0; i < maxlen; ++i) {
    float2 g[NCOH];
#pragma unroll
    for (int u = 0; u < NCOH; ++u) {
      g[u] = make_float2(0.f, 0.f);
      if (i < len[u]) {
        int s = csr8[start[u] + i];
        g[u] = __half22float2(h2[s * 64 + lane]);
      }
    }
#pragma unroll
    for (int u = 0; u < NCOH; ++u) {
      ax += g[u].x;
      ay += g[u].y;
    }
  }
  float dv = dinv[v];
  ((__half2*)agg)[v * 64 + lane] = __floats2half2_rn(ax * dv, ay * dv);
}

// ---------------- MFMA GEMM + LN (+ReLU -> fp16 h' | + MFMA head -> out) ----------------

__global__ __launch_bounds__(256) void mfma_gemm_kernel(
    const __half* __restrict__ aggh, const __half* __restrict__ Wt,
    const float* __restrict__ bias, const float* __restrict__ gam,
    const float* __restrict__ bet, const float* __restrict__ dinv,
    __half* __restrict__ hout,
    const __half* __restrict__ rW1t, const float* __restrict__ rb1,
    const float* __restrict__ rW2, const float* __restrict__ rb2,
    float* __restrict__ out, int n, int mode) {
  __shared__ __align__(16) __half smem[128 * 136];  // Wt staged; later aliased as tile
  int tid = threadIdx.x;
  int v0 = blockIdx.x * 64;
  int lane = tid & 63;
  int wv = tid >> 6;
  int m = lane & 15;
  int q = lane >> 4;

#pragma unroll
  for (int i = 0; i < 8; ++i) {
    int u = tid + i * 256;
    int row = u >> 4, seg = u & 15;
    *(uint4*)&smem[row * 136 + seg * 8] = *(const uint4*)&Wt[row * 128 + seg * 8];
  }

  int row = v0 + wv * 16 + m;
  int rowc = row < n ? row : n - 1;
  const __half* abase = aggh + (size_t)rowc * 128 + q * 8;
  half8 afrag[4];
#pragma unroll
  for (int kt = 0; kt < 4; ++kt) afrag[kt] = *(const half8*)(abase + kt * 32);

  __syncthreads();

  f32x4 acc[8];
#pragma unroll
  for (int c = 0; c < 8; ++c) acc[c] = (f32x4){0.f, 0.f, 0.f, 0.f};
#pragma unroll
  for (int kt = 0; kt < 4; ++kt) {
#pragma unroll
    for (int c = 0; c < 8; ++c) {
      half8 b = *(const half8*)&smem[(c * 16 + m) * 136 + kt * 32 + q * 8];
      acc[c] = __builtin_amdgcn_mfma_f32_16x16x32_f16(afrag[kt], b, acc[c], 0, 0, 0);
    }
  }

#pragma unroll
  for (int c = 0; c < 8; ++c) {
    float bcol = bias[c * 16 + m];
#pragma unroll
    for (int r = 0; r < 4; ++r) acc[c][r] += bcol;
  }
  float mean[4], rstd[4], dvr[4];
#pragma unroll
  for (int r = 0; r < 4; ++r) {
    float s = 0.f, q2 = 0.f;
#pragma unroll
    for (int c = 0; c < 8; ++c) {
      float vv = acc[c][r];
      s += vv;
      q2 += vv * vv;
    }
#pragma unroll
    for (int off = 8; off >= 1; off >>= 1) {
      s += __shfl_xor(s, off, 16);
      q2 += __shfl_xor(q2, off, 16);
    }
    float mu = s * (1.f / HDIM);
    float var = fmaxf(q2 * (1.f / HDIM) - mu * mu, 0.f);
    mean[r] = mu;
    rstd[r] = rsqrtf(var + LN_EPS);
    int vr = v0 + wv * 16 + q * 4 + r;
    dvr[r] = (mode == 1 && vr < n) ? dinv[vr] : 1.f;
  }

  __syncthreads();
  __half* tile = smem;  // 64 x 136
#pragma unroll
  for (int c = 0; c < 8; ++c) {
    float g = gam[c * 16 + m], bb = bet[c * 16 + m];
#pragma unroll
    for (int r = 0; r < 4; ++r) {
      float y = fmaf((acc[c][r] - mean[r]) * rstd[r], g, bb);
      if (mode == 1) y = fmaxf(y, 0.f) * dvr[r];
      tile[(wv * 16 + q * 4 + r) * 136 + c * 16 + m] = __float2half(y);
    }
  }
  __syncthreads();

  if (mode == 1) {
#pragma unroll
    for (int i = 0; i < 4; ++i) {
      int u = tid + i * 256;
      int r = u >> 4, seg = u & 15;
      int v = v0 + r;
      if (v < n) *(uint4*)&hout[(size_t)v * 128 + seg * 8] = *(const uint4*)&tile[r * 136 + seg * 8];
    }
    return;
  }

  f32x4 hacc[4];
#pragma unroll
  for (int c = 0; c < 4; ++c) hacc[c] = (f32x4){0.f, 0.f, 0.f, 0.f};
#pragma unroll
  for (int kt = 0; kt < 4; ++kt) {
    half8 a = *(const half8*)&tile[(wv * 16 + m) * 136 + kt * 32 + q * 8];
#pragma unroll
    for (int c = 0; c < 4; ++c) {
      half8 b = *(const half8*)&rW1t[(c * 16 + m) * 128 + kt * 32 + q * 8];
      hacc[c] = __builtin_amdgcn_mfma_f32_16x16x32_f16(a, b, hacc[c], 0, 0, 0);
    }
  }
  float p[4] = {0.f, 0.f, 0.f, 0.f};
#pragma unroll
  for (int c = 0; c < 4; ++c) {
    float rb = rb1[c * 16 + m], w2 = rW2[c * 16 + m];
#pragma unroll
    for (int r = 0; r < 4; ++r) {
      float hv = fmaxf(hacc[c][r] + rb, 0.f);
      p[r] = fmaf(hv, w2, p[r]);
    }
  }
#pragma unroll
  for (int r = 0; r < 4; ++r) {
#pragma unroll
    for (int off = 8; off >= 1; off >>= 1) p[r] += __shfl_xor(p[r], off, 16);
  }
  if (m == 0) {
    float rb2v = rb2[0];
#pragma unroll
    for (int r = 0; r < 4; ++r) {
      int v = v0 + wv * 16 + q * 4 + r;
      if (v < n) out[v] = 1.f / (1.f + expf(-(p[r] + rb2v)));
    }
  }
}

// ---------------- Launch ----------------

extern "C" void kernel_launch(void* const* d_in, const int* in_sizes, int n_in,
                              void* d_out, int out_size, void* d_ws, size_t ws_size,
                              hipStream_t stream) {
  const float* x   = (const float*)d_in[0];
  const int*  eidx = (const int*)d_in[1];
  const float* W1  = (const float*)d_in[2];
  const float* b1  = (const float*)d_in[3];
  const float* W2  = (const float*)d_in[4];
  const float* b2  = (const float*)d_in[5];
  const float* W3  = (const float*)d_in[6];
  const float* b3  = (const float*)d_in[7];
  const float* g1  = (const float*)d_in[8];
  const float* be1 = (const float*)d_in[9];
  const float* g2  = (const float*)d_in[10];
  const float* be2 = (const float*)d_in[11];
  const float* g3  = (const float*)d_in[12];
  const float* be3 = (const float*)d_in[13];
  const float* rW1 = (const float*)d_in[14];
  const float* rb1 = (const float*)d_in[15];
  const float* rW2 = (const float*)d_in[16];
  const float* rb2 = (const float*)d_in[17];

  int N = in_sizes[0] / 6;
  int E = in_sizes[1] / 2;
  const int* srcp = eidx;
  const int* dstp = eidx + E;
  float* out = (float*)d_out;

  char* p = (char*)d_ws;
  auto alloc = [&](size_t bytes) -> void* {
    void* r = (void*)p;
    p += (bytes + 255) & ~(size_t)255;
    return r;
  };
  int*    counts8  = (int*)alloc((size_t)NCOH * N * 4);
  int*    rowptr8  = (int*)alloc(((size_t)NCOH * N + 1) * 4);
  int*    cursor8  = (int*)alloc((size_t)NCOH * N * 4);
  float*  dinvp    = (float*)alloc((size_t)N * 4);
  int*    blocksum = (int*)alloc((size_t)1024 * 4);
  int*    csr8     = (int*)alloc((size_t)E * 4);
  float*  xs       = (float*)alloc((size_t)N * 6 * 4);
  __half* h16_a    = (__half*)alloc((size_t)N * HDIM * 2);
  __half* h16_b    = (__half*)alloc((size_t)N * HDIM * 2);
  __half* aggbuf   = (__half*)alloc((size_t)N * HDIM * 2);
  __half* w2t      = (__half*)alloc((size_t)HDIM * HDIM * 2);
  __half* w3t      = (__half*)alloc((size_t)HDIM * HDIM * 2);
  __half* rw1t     = (__half*)alloc((size_t)64 * HDIM * 2);

  int M8 = NCOH * N;
  int nscan8 = (M8 + 2047) / 2048;  // 196 blocks for N=50k

  hipMemsetAsync(counts8, 0, (size_t)M8 * 4, stream);
  count_kernel<<<(E + 255) / 256, 256, 0, stream>>>(dstp, counts8, E, N);
  dinv_kernel<<<(N + 255) / 256, 256, 0, stream>>>(counts8, dinvp, N);
  scan_sum_kernel<<<nscan8, 256, 0, stream>>>(counts8, blocksum, M8);
  scan2_kernel<<<1, 256, 0, stream>>>(blocksum, nscan8);
  scan_emit_kernel<<<nscan8, 256, 0, stream>>>(counts8, blocksum, rowptr8, cursor8, M8, nscan8);
  fill_kernel<<<(E + 255) / 256, 256, 0, stream>>>(srcp, dstp, cursor8, csr8, E, N);
  prep_kernel<<<(N * 6 + 40960 + 255) / 256, 256, 0, stream>>>(x, dinvp, xs, W2, W3, rW1,
                                                               w2t, w3t, rw1t, N);

  int nw = (N + 3) / 4;
  int nb = (N + 63) / 64;
  layer1_kernel<<<nw, 256, 0, stream>>>(xs, W1, b1, g1, be1, rowptr8, csr8, dinvp, h16_a, N);
  agg_kernel<<<nw, 256, 0, stream>>>(h16_a, rowptr8, csr8, dinvp, aggbuf, N);
  mfma_gemm_kernel<<<nb, 256, 0, stream>>>(aggbuf, w2t, b2, g2, be2, dinvp, h16_b,
                                           rw1t, rb1, rW2, rb2, out, N, 1);
  agg_kernel<<<nw, 256, 0, stream>>>(h16_b, rowptr8, csr8, dinvp, aggbuf, N);
  mfma_gemm_kernel<<<nb, 256, 0, stream>>>(aggbuf, w3t, b3, g3, be3, dinvp, h16_b,
                                           rw1t, rb1, rW2, rb2, out, N, 2);
}

// Round 10
// 354.433 us; speedup vs baseline: 1.1558x; 1.1558x over previous
//
#include <hip/hip_runtime.h>
#include <hip/hip_fp16.h>
#include <math.h>

#define HDIM 128
#define LN_EPS 1e-5f
#define NCOH 8  // XCD cohorts (blockIdx % 8 ~ XCD round-robin heuristic; perf-only)

typedef _Float16 half8 __attribute__((ext_vector_type(8)));
typedef float f32x4 __attribute__((ext_vector_type(4)));

// h'[v] = dinv[v]*h[v]; agg[v] = dinv[v]*(sum_{s in N(v)} h'[s] + h'[v]).
// CSR is cohort-sharded x-major (kills fill write-amplification). Consumers
// preload indices lane-parallel and broadcast via shfl -> no scalar memory in
// the gather loop, 8 independent row-gathers in flight.

// ---------------- CSR build ----------------

__global__ void count_kernel(const int* __restrict__ dst, int* __restrict__ counts8,
                             int E, int n) {
  int e = blockIdx.x * blockDim.x + threadIdx.x;
  int x = blockIdx.x & (NCOH - 1);
  if (e < E) atomicAdd(&counts8[x * n + dst[e]], 1);
}

__global__ void dinv_kernel(const int* __restrict__ counts8, float* __restrict__ dinv, int n) {
  int i = blockIdx.x * 256 + threadIdx.x;
  if (i < n) {
    int s = 0;
#pragma unroll
    for (int x = 0; x < NCOH; ++x) s += counts8[x * n + i];
    dinv[i] = rsqrtf((float)(s + 1));  // +1 self-loop
  }
}

// Hierarchical scan over the 8N cohort-sharded counts (256 threads, 8 elems/thread).
__global__ __launch_bounds__(256) void scan_sum_kernel(const int* __restrict__ in,
                                                       int* __restrict__ blocksum, int n) {
  int base = blockIdx.x * 2048;
  int tid = threadIdx.x;
  int sum = 0;
#pragma unroll
  for (int j = 0; j < 8; ++j) {
    int i = base + tid * 8 + j;
    if (i < n) sum += in[i];
  }
#pragma unroll
  for (int off = 32; off >= 1; off >>= 1) sum += __shfl_xor(sum, off, 64);
  __shared__ int wsum[4];
  if ((tid & 63) == 0) wsum[tid >> 6] = sum;
  __syncthreads();
  if (tid == 0) blocksum[blockIdx.x] = wsum[0] + wsum[1] + wsum[2] + wsum[3];
}

__global__ __launch_bounds__(256) void scan2_kernel(int* __restrict__ blocksum, int nblk) {
  __shared__ int sh[256];
  int tid = threadIdx.x;
  sh[tid] = (tid < nblk) ? blocksum[tid] : 0;
  __syncthreads();
  for (int off = 1; off < 256; off <<= 1) {
    int t = (tid >= off) ? sh[tid - off] : 0;
    __syncthreads();
    sh[tid] += t;
    __syncthreads();
  }
  if (tid < nblk) blocksum[tid] = sh[tid];  // inclusive
}

__global__ __launch_bounds__(256) void scan_emit_kernel(const int* __restrict__ in,
                                                        const int* __restrict__ blocksum,
                                                        int* __restrict__ rowptr8,
                                                        int* __restrict__ cursor8, int n, int nblk) {
  int base = blockIdx.x * 2048;
  int tid = threadIdx.x;
  int c[8];
  int s = 0;
#pragma unroll
  for (int j = 0; j < 8; ++j) {
    int i = base + tid * 8 + j;
    c[j] = (i < n) ? in[i] : 0;
    s += c[j];
  }
  int lane = tid & 63, wid = tid >> 6;
  int incl = s;
#pragma unroll
  for (int off = 1; off < 64; off <<= 1) {
    int t = __shfl_up(incl, off, 64);
    if (lane >= off) incl += t;
  }
  __shared__ int wsum[4];
  if (lane == 63) wsum[wid] = incl;
  __syncthreads();
  int woff = 0;
  for (int w = 0; w < wid; ++w) woff += wsum[w];
  int p = (blockIdx.x == 0 ? 0 : blocksum[blockIdx.x - 1]) + woff + (incl - s);
#pragma unroll
  for (int j = 0; j < 8; ++j) {
    int i = base + tid * 8 + j;
    if (i < n) {
      rowptr8[i] = p;
      cursor8[i] = p;
    }
    p += c[j];
  }
  if (blockIdx.x == nblk - 1 && tid == 255) rowptr8[n] = blocksum[nblk - 1];
}

__global__ void fill_kernel(const int* __restrict__ src, const int* __restrict__ dst,
                            int* __restrict__ cursor8, int* __restrict__ csr8, int E, int n) {
  int e = blockIdx.x * blockDim.x + threadIdx.x;
  int x = blockIdx.x & (NCOH - 1);
  if (e < E) {
    int pos = atomicAdd(&cursor8[x * n + dst[e]], 1);
    csr8[pos] = src[e];  // cohort-owned contiguous region -> XCD-local L2 lines
  }
}

// ---------------- Prep: x' = dinv*x ; fp16-transposed weights (fused) ----------------

__global__ void prep_kernel(const float* __restrict__ x, const float* __restrict__ dinv,
                            float* __restrict__ xs, const float* __restrict__ W2,
                            const float* __restrict__ W3, const float* __restrict__ rW1,
                            __half* __restrict__ w2t, __half* __restrict__ w3t,
                            __half* __restrict__ rw1t, int n) {
  int idx = blockIdx.x * 256 + threadIdx.x;
  int nx = n * 6;
  if (idx < nx) {
    xs[idx] = x[idx] * dinv[idx / 6];
    return;
  }
  int i = idx - nx;
  if (i < 16384) {
    int nn = i >> 7, k = i & 127;
    w2t[i] = __float2half(W2[k * 128 + nn]);
  } else if (i < 32768) {
    int j = i - 16384;
    int nn = j >> 7, k = j & 127;
    w3t[j] = __float2half(W3[k * 128 + nn]);
  } else if (i < 40960) {
    int j = i - 32768;
    int nn = j >> 7, k = j & 127;
    rw1t[j] = __float2half(rW1[k * 64 + nn]);
  }
}

// ---------------- Layer 1: one wave/node over 8 segments; 6->128 GEMM + LN + ReLU ----------

__global__ __launch_bounds__(256) void layer1_kernel(
    const float* __restrict__ xs, const float* __restrict__ W1,
    const float* __restrict__ b1, const float* __restrict__ gam,
    const float* __restrict__ bet, const int* __restrict__ rowptr8,
    const int* __restrict__ csr8, const float* __restrict__ dinv,
    __half* __restrict__ hout, int n) {
  int v = blockIdx.x * 4 + (threadIdx.x >> 6);
  if (v >= n) return;
  int lane = threadIdx.x & 63;
  int sx = 0, ex = 0;
  if (lane < NCOH) {
    sx = rowptr8[lane * n + v];
    ex = rowptr8[lane * n + v + 1];
  }
  int u = lane & 7;
  int su = __shfl(sx, u, 64);
  int lu = __shfl(ex, u, 64) - su;
  float a[6] = {0.f, 0.f, 0.f, 0.f, 0.f, 0.f};
  for (int i = lane >> 3; i < lu; i += 8) {
    int s = csr8[su + i];
#pragma unroll
    for (int j = 0; j < 6; ++j) a[j] += xs[s * 6 + j];
  }
  if (lane == 0) {
#pragma unroll
    for (int j = 0; j < 6; ++j) a[j] += xs[v * 6 + j];  // self-loop
  }
#pragma unroll
  for (int off = 32; off >= 1; off >>= 1) {
#pragma unroll
    for (int j = 0; j < 6; ++j) a[j] += __shfl_xor(a[j], off, 64);
  }
  float dv = dinv[v];
#pragma unroll
  for (int j = 0; j < 6; ++j) a[j] *= dv;
  int f0 = lane, f1 = lane + 64;
  float o0 = b1[f0], o1 = b1[f1];
#pragma unroll
  for (int j = 0; j < 6; ++j) {
    o0 = fmaf(a[j], W1[j * HDIM + f0], o0);
    o1 = fmaf(a[j], W1[j * HDIM + f1], o1);
  }
  float s = o0 + o1, q = o0 * o0 + o1 * o1;
#pragma unroll
  for (int off = 32; off >= 1; off >>= 1) {
    s += __shfl_xor(s, off, 64);
    q += __shfl_xor(q, off, 64);
  }
  float m = s * (1.0f / HDIM);
  float var = fmaxf(q * (1.0f / HDIM) - m * m, 0.f);
  float rs = rsqrtf(var + LN_EPS);
  float y0 = fmaxf(fmaf((o0 - m) * rs, gam[f0], bet[f0]), 0.f);
  float y1 = fmaxf(fmaf((o1 - m) * rs, gam[f1], bet[f1]), 0.f);
  hout[v * HDIM + f0] = __float2half(y0 * dv);  // store h' = dinv*h
  hout[v * HDIM + f1] = __float2half(y1 * dv);
}

// ---------------- Aggregation: one wave/node; lane-parallel index preload + shfl bcast ------
// Up to 64 indices fetched in ONE lane-parallel load (lane p -> (segment,offset) via an
// in-register prefix table), then the gather loop broadcasts via __shfl (no memory) and
// issues 8 independent 256B row-gathers per group.

__global__ __launch_bounds__(256) void agg_kernel(
    const __half* __restrict__ hin, const int* __restrict__ rowptr8,
    const int* __restrict__ csr8, const float* __restrict__ dinv,
    __half* __restrict__ agg, int n) {
  int v = blockIdx.x * 4 + (threadIdx.x >> 6);
  if (v >= n) return;
  int lane = threadIdx.x & 63;
  const __half2* h2 = (const __half2*)hin;
  float2 hf = __half22float2(h2[v * 64 + lane]);
  float ax = hf.x, ay = hf.y;  // self-loop
  int sx = 0, ex = 0;
  if (lane < NCOH) {
    sx = rowptr8[lane * n + v];
    ex = rowptr8[lane * n + v + 1];
  }
  int starts[NCOH], L[NCOH + 1];
  L[0] = 0;
#pragma unroll
  for (int u = 0; u < NCOH; ++u) {
    starts[u] = __shfl(sx, u, 64);
    L[u + 1] = L[u] + (__shfl(ex, u, 64) - starts[u]);
  }
  int deg = L[NCOH];
  for (int c0 = 0; c0 < deg; c0 += 64) {
    int p = c0 + lane;
    int myidx = 0;
    if (p < deg) {
      int u = 0;
#pragma unroll
      for (int t = 1; t < NCOH; ++t) u += (p >= L[t]);
      myidx = csr8[starts[u] + (p - L[u])];  // one lane-parallel load for 64 indices
    }
    int cnt = min(deg - c0, 64);
    for (int j = 0; j < cnt; j += 8) {
      float2 g[8];
#pragma unroll
      for (int u = 0; u < 8; ++u) {
        g[u] = make_float2(0.f, 0.f);
        int jj = j + u;
        if (jj < cnt) {  // wave-uniform guard (only last group partial)
          int s = __shfl(myidx, jj, 64);  // register broadcast, no memory
          g[u] = __half22float2(h2[s * 64 + lane]);
        }
      }
#pragma unroll
      for (int u = 0; u < 8; ++u) {
        ax += g[u].x;
        ay += g[u].y;
      }
    }
  }
  float dv = dinv[v];
  ((__half2*)agg)[v * 64 + lane] = __floats2half2_rn(ax * dv, ay * dv);
}

// ---------------- MFMA GEMM + LN (+ReLU -> fp16 h' | + MFMA head -> out) ----------------

__global__ __launch_bounds__(256) void mfma_gemm_kernel(
    const __half* __restrict__ aggh, const __half* __restrict__ Wt,
    const float* __restrict__ bias, const float* __restrict__ gam,
    const float* __restrict__ bet, const float* __restrict__ dinv,
    __half* __restrict__ hout,
    const __half* __restrict__ rW1t, const float* __restrict__ rb1,
    const float* __restrict__ rW2, const float* __restrict__ rb2,
    float* __restrict__ out, int n, int mode) {
  __shared__ __align__(16) __half smem[128 * 136];  // Wt staged; later aliased as tile
  int tid = threadIdx.x;
  int v0 = blockIdx.x * 64;
  int lane = tid & 63;
  int wv = tid >> 6;
  int m = lane & 15;
  int q = lane >> 4;

#pragma unroll
  for (int i = 0; i < 8; ++i) {
    int u = tid + i * 256;
    int row = u >> 4, seg = u & 15;
    *(uint4*)&smem[row * 136 + seg * 8] = *(const uint4*)&Wt[row * 128 + seg * 8];
  }

  int row = v0 + wv * 16 + m;
  int rowc = row < n ? row : n - 1;
  const __half* abase = aggh + (size_t)rowc * 128 + q * 8;
  half8 afrag[4];
#pragma unroll
  for (int kt = 0; kt < 4; ++kt) afrag[kt] = *(const half8*)(abase + kt * 32);

  __syncthreads();

  f32x4 acc[8];
#pragma unroll
  for (int c = 0; c < 8; ++c) acc[c] = (f32x4){0.f, 0.f, 0.f, 0.f};
#pragma unroll
  for (int kt = 0; kt < 4; ++kt) {
#pragma unroll
    for (int c = 0; c < 8; ++c) {
      half8 b = *(const half8*)&smem[(c * 16 + m) * 136 + kt * 32 + q * 8];
      acc[c] = __builtin_amdgcn_mfma_f32_16x16x32_f16(afrag[kt], b, acc[c], 0, 0, 0);
    }
  }

#pragma unroll
  for (int c = 0; c < 8; ++c) {
    float bcol = bias[c * 16 + m];
#pragma unroll
    for (int r = 0; r < 4; ++r) acc[c][r] += bcol;
  }
  float mean[4], rstd[4], dvr[4];
#pragma unroll
  for (int r = 0; r < 4; ++r) {
    float s = 0.f, q2 = 0.f;
#pragma unroll
    for (int c = 0; c < 8; ++c) {
      float vv = acc[c][r];
      s += vv;
      q2 += vv * vv;
    }
#pragma unroll
    for (int off = 8; off >= 1; off >>= 1) {
      s += __shfl_xor(s, off, 16);
      q2 += __shfl_xor(q2, off, 16);
    }
    float mu = s * (1.f / HDIM);
    float var = fmaxf(q2 * (1.f / HDIM) - mu * mu, 0.f);
    mean[r] = mu;
    rstd[r] = rsqrtf(var + LN_EPS);
    int vr = v0 + wv * 16 + q * 4 + r;
    dvr[r] = (mode == 1 && vr < n) ? dinv[vr] : 1.f;
  }

  __syncthreads();
  __half* tile = smem;  // 64 x 136
#pragma unroll
  for (int c = 0; c < 8; ++c) {
    float g = gam[c * 16 + m], bb = bet[c * 16 + m];
#pragma unroll
    for (int r = 0; r < 4; ++r) {
      float y = fmaf((acc[c][r] - mean[r]) * rstd[r], g, bb);
      if (mode == 1) y = fmaxf(y, 0.f) * dvr[r];
      tile[(wv * 16 + q * 4 + r) * 136 + c * 16 + m] = __float2half(y);
    }
  }
  __syncthreads();

  if (mode == 1) {
#pragma unroll
    for (int i = 0; i < 4; ++i) {
      int u = tid + i * 256;
      int r = u >> 4, seg = u & 15;
      int v = v0 + r;
      if (v < n) *(uint4*)&hout[(size_t)v * 128 + seg * 8] = *(const uint4*)&tile[r * 136 + seg * 8];
    }
    return;
  }

  f32x4 hacc[4];
#pragma unroll
  for (int c = 0; c < 4; ++c) hacc[c] = (f32x4){0.f, 0.f, 0.f, 0.f};
#pragma unroll
  for (int kt = 0; kt < 4; ++kt) {
    half8 a = *(const half8*)&tile[(wv * 16 + m) * 136 + kt * 32 + q * 8];
#pragma unroll
    for (int c = 0; c < 4; ++c) {
      half8 b = *(const half8*)&rW1t[(c * 16 + m) * 128 + kt * 32 + q * 8];
      hacc[c] = __builtin_amdgcn_mfma_f32_16x16x32_f16(a, b, hacc[c], 0, 0, 0);
    }
  }
  float p[4] = {0.f, 0.f, 0.f, 0.f};
#pragma unroll
  for (int c = 0; c < 4; ++c) {
    float rb = rb1[c * 16 + m], w2 = rW2[c * 16 + m];
#pragma unroll
    for (int r = 0; r < 4; ++r) {
      float hv = fmaxf(hacc[c][r] + rb, 0.f);
      p[r] = fmaf(hv, w2, p[r]);
    }
  }
#pragma unroll
  for (int r = 0; r < 4; ++r) {
#pragma unroll
    for (int off = 8; off >= 1; off >>= 1) p[r] += __shfl_xor(p[r], off, 16);
  }
  if (m == 0) {
    float rb2v = rb2[0];
#pragma unroll
    for (int r = 0; r < 4; ++r) {
      int v = v0 + wv * 16 + q * 4 + r;
      if (v < n) out[v] = 1.f / (1.f + expf(-(p[r] + rb2v)));
    }
  }
}

// ---------------- Launch ----------------

extern "C" void kernel_launch(void* const* d_in, const int* in_sizes, int n_in,
                              void* d_out, int out_size, void* d_ws, size_t ws_size,
                              hipStream_t stream) {
  const float* x   = (const float*)d_in[0];
  const int*  eidx = (const int*)d_in[1];
  const float* W1  = (const float*)d_in[2];
  const float* b1  = (const float*)d_in[3];
  const float* W2  = (const float*)d_in[4];
  const float* b2  = (const float*)d_in[5];
  const float* W3  = (const float*)d_in[6];
  const float* b3  = (const float*)d_in[7];
  const float* g1  = (const float*)d_in[8];
  const float* be1 = (const float*)d_in[9];
  const float* g2  = (const float*)d_in[10];
  const float* be2 = (const float*)d_in[11];
  const float* g3  = (const float*)d_in[12];
  const float* be3 = (const float*)d_in[13];
  const float* rW1 = (const float*)d_in[14];
  const float* rb1 = (const float*)d_in[15];
  const float* rW2 = (const float*)d_in[16];
  const float* rb2 = (const float*)d_in[17];

  int N = in_sizes[0] / 6;
  int E = in_sizes[1] / 2;
  const int* srcp = eidx;
  const int* dstp = eidx + E;
  float* out = (float*)d_out;

  char* p = (char*)d_ws;
  auto alloc = [&](size_t bytes) -> void* {
    void* r = (void*)p;
    p += (bytes + 255) & ~(size_t)255;
    return r;
  };
  int*    counts8  = (int*)alloc((size_t)NCOH * N * 4);
  int*    rowptr8  = (int*)alloc(((size_t)NCOH * N + 1) * 4);
  int*    cursor8  = (int*)alloc((size_t)NCOH * N * 4);
  float*  dinvp    = (float*)alloc((size_t)N * 4);
  int*    blocksum = (int*)alloc((size_t)1024 * 4);
  int*    csr8     = (int*)alloc((size_t)E * 4);
  float*  xs       = (float*)alloc((size_t)N * 6 * 4);
  __half* h16_a    = (__half*)alloc((size_t)N * HDIM * 2);
  __half* h16_b    = (__half*)alloc((size_t)N * HDIM * 2);
  __half* aggbuf   = (__half*)alloc((size_t)N * HDIM * 2);
  __half* w2t      = (__half*)alloc((size_t)HDIM * HDIM * 2);
  __half* w3t      = (__half*)alloc((size_t)HDIM * HDIM * 2);
  __half* rw1t     = (__half*)alloc((size_t)64 * HDIM * 2);

  int M8 = NCOH * N;
  int nscan8 = (M8 + 2047) / 2048;  // 196 blocks for N=50k

  hipMemsetAsync(counts8, 0, (size_t)M8 * 4, stream);
  count_kernel<<<(E + 255) / 256, 256, 0, stream>>>(dstp, counts8, E, N);
  dinv_kernel<<<(N + 255) / 256, 256, 0, stream>>>(counts8, dinvp, N);
  scan_sum_kernel<<<nscan8, 256, 0, stream>>>(counts8, blocksum, M8);
  scan2_kernel<<<1, 256, 0, stream>>>(blocksum, nscan8);
  scan_emit_kernel<<<nscan8, 256, 0, stream>>>(counts8, blocksum, rowptr8, cursor8, M8, nscan8);
  fill_kernel<<<(E + 255) / 256, 256, 0, stream>>>(srcp, dstp, cursor8, csr8, E, N);
  prep_kernel<<<(N * 6 + 40960 + 255) / 256, 256, 0, stream>>>(x, dinvp, xs, W2, W3, rW1,
                                                               w2t, w3t, rw1t, N);

  int nw = (N + 3) / 4;
  int nb = (N + 63) / 64;
  layer1_kernel<<<nw, 256, 0, stream>>>(xs, W1, b1, g1, be1, rowptr8, csr8, dinvp, h16_a, N);
  agg_kernel<<<nw, 256, 0, stream>>>(h16_a, rowptr8, csr8, dinvp, aggbuf, N);
  mfma_gemm_kernel<<<nb, 256, 0, stream>>>(aggbuf, w2t, b2, g2, be2, dinvp, h16_b,
                                           rw1t, rb1, rW2, rb2, out, N, 1);
  agg_kernel<<<nw, 256, 0, stream>>>(h16_b, rowptr8, csr8, dinvp, aggbuf, N);
  mfma_gemm_kernel<<<nb, 256, 0, stream>>>(aggbuf, w3t, b3, g3, be3, dinvp, h16_b,
                                           rw1t, rb1, rW2, rb2, out, N, 2);
}

// Round 11
// 324.615 us; speedup vs baseline: 1.2620x; 1.0919x over previous
//
#include <hip/hip_runtime.h>
#include <hip/hip_fp16.h>
#include <math.h>

#define HDIM 128
#define LN_EPS 1e-5f
#define NCOH 8  // XCD cohorts (blockIdx % 8 ~ XCD round-robin heuristic; perf-only)

typedef _Float16 half8 __attribute__((ext_vector_type(8)));
typedef float f32x4 __attribute__((ext_vector_type(4)));

// h'[v] = dinv[v]*h[v]; agg[v] = dinv[v]*(sum_{s in N(v)} h'[s] + h'[v]).
// CSR is cohort-sharded x-major (kills fill write-amplification). Consumers
// preload indices lane-parallel (lane p -> (segment,offset) via in-register
// prefix table); agg broadcasts via shfl with a 16-deep gather pipeline.

// ---------------- CSR build ----------------

__global__ void count_kernel(const int* __restrict__ dst, int* __restrict__ counts8,
                             int E, int n) {
  int e = blockIdx.x * blockDim.x + threadIdx.x;
  int x = blockIdx.x & (NCOH - 1);
  if (e < E) atomicAdd(&counts8[x * n + dst[e]], 1);
}

__global__ void dinv_kernel(const int* __restrict__ counts8, float* __restrict__ dinv, int n) {
  int i = blockIdx.x * 256 + threadIdx.x;
  if (i < n) {
    int s = 0;
#pragma unroll
    for (int x = 0; x < NCOH; ++x) s += counts8[x * n + i];
    dinv[i] = rsqrtf((float)(s + 1));  // +1 self-loop
  }
}

// Hierarchical scan over the 8N cohort-sharded counts (256 threads, 8 elems/thread).
__global__ __launch_bounds__(256) void scan_sum_kernel(const int* __restrict__ in,
                                                       int* __restrict__ blocksum, int n) {
  int base = blockIdx.x * 2048;
  int tid = threadIdx.x;
  int sum = 0;
#pragma unroll
  for (int j = 0; j < 8; ++j) {
    int i = base + tid * 8 + j;
    if (i < n) sum += in[i];
  }
#pragma unroll
  for (int off = 32; off >= 1; off >>= 1) sum += __shfl_xor(sum, off, 64);
  __shared__ int wsum[4];
  if ((tid & 63) == 0) wsum[tid >> 6] = sum;
  __syncthreads();
  if (tid == 0) blocksum[blockIdx.x] = wsum[0] + wsum[1] + wsum[2] + wsum[3];
}

__global__ __launch_bounds__(256) void scan2_kernel(int* __restrict__ blocksum, int nblk) {
  __shared__ int sh[256];
  int tid = threadIdx.x;
  sh[tid] = (tid < nblk) ? blocksum[tid] : 0;
  __syncthreads();
  for (int off = 1; off < 256; off <<= 1) {
    int t = (tid >= off) ? sh[tid - off] : 0;
    __syncthreads();
    sh[tid] += t;
    __syncthreads();
  }
  if (tid < nblk) blocksum[tid] = sh[tid];  // inclusive
}

__global__ __launch_bounds__(256) void scan_emit_kernel(const int* __restrict__ in,
                                                        const int* __restrict__ blocksum,
                                                        int* __restrict__ rowptr8,
                                                        int* __restrict__ cursor8, int n, int nblk) {
  int base = blockIdx.x * 2048;
  int tid = threadIdx.x;
  int c[8];
  int s = 0;
#pragma unroll
  for (int j = 0; j < 8; ++j) {
    int i = base + tid * 8 + j;
    c[j] = (i < n) ? in[i] : 0;
    s += c[j];
  }
  int lane = tid & 63, wid = tid >> 6;
  int incl = s;
#pragma unroll
  for (int off = 1; off < 64; off <<= 1) {
    int t = __shfl_up(incl, off, 64);
    if (lane >= off) incl += t;
  }
  __shared__ int wsum[4];
  if (lane == 63) wsum[wid] = incl;
  __syncthreads();
  int woff = 0;
  for (int w = 0; w < wid; ++w) woff += wsum[w];
  int p = (blockIdx.x == 0 ? 0 : blocksum[blockIdx.x - 1]) + woff + (incl - s);
#pragma unroll
  for (int j = 0; j < 8; ++j) {
    int i = base + tid * 8 + j;
    if (i < n) {
      rowptr8[i] = p;
      cursor8[i] = p;
    }
    p += c[j];
  }
  if (blockIdx.x == nblk - 1 && tid == 255) rowptr8[n] = blocksum[nblk - 1];
}

__global__ void fill_kernel(const int* __restrict__ src, const int* __restrict__ dst,
                            int* __restrict__ cursor8, int* __restrict__ csr8, int E, int n) {
  int e = blockIdx.x * blockDim.x + threadIdx.x;
  int x = blockIdx.x & (NCOH - 1);
  if (e < E) {
    int pos = atomicAdd(&cursor8[x * n + dst[e]], 1);
    csr8[pos] = src[e];  // cohort-owned contiguous region -> XCD-local L2 lines
  }
}

// ---------------- Prep: x' = dinv*x ; fp16-transposed weights (fused) ----------------

__global__ void prep_kernel(const float* __restrict__ x, const float* __restrict__ dinv,
                            float* __restrict__ xs, const float* __restrict__ W2,
                            const float* __restrict__ W3, const float* __restrict__ rW1,
                            __half* __restrict__ w2t, __half* __restrict__ w3t,
                            __half* __restrict__ rw1t, int n) {
  int idx = blockIdx.x * 256 + threadIdx.x;
  int nx = n * 6;
  if (idx < nx) {
    xs[idx] = x[idx] * dinv[idx / 6];
    return;
  }
  int i = idx - nx;
  if (i < 16384) {
    int nn = i >> 7, k = i & 127;
    w2t[i] = __float2half(W2[k * 128 + nn]);
  } else if (i < 32768) {
    int j = i - 16384;
    int nn = j >> 7, k = j & 127;
    w3t[j] = __float2half(W3[k * 128 + nn]);
  } else if (i < 40960) {
    int j = i - 32768;
    int nn = j >> 7, k = j & 127;
    rw1t[j] = __float2half(rW1[k * 64 + nn]);
  }
}

// ---------------- Layer 1: one wave/node; lane-owned edges, 6->128 GEMM + LN + ReLU ----------

__global__ __launch_bounds__(256) void layer1_kernel(
    const float* __restrict__ xs, const float* __restrict__ W1,
    const float* __restrict__ b1, const float* __restrict__ gam,
    const float* __restrict__ bet, const int* __restrict__ rowptr8,
    const int* __restrict__ csr8, const float* __restrict__ dinv,
    __half* __restrict__ hout, int n) {
  int v = blockIdx.x * 4 + (threadIdx.x >> 6);
  if (v >= n) return;
  int lane = threadIdx.x & 63;
  int sx = 0, ex = 0;
  if (lane < NCOH) {
    sx = rowptr8[lane * n + v];
    ex = rowptr8[lane * n + v + 1];
  }
  int starts[NCOH], L[NCOH + 1];
  L[0] = 0;
#pragma unroll
  for (int u = 0; u < NCOH; ++u) {
    starts[u] = __shfl(sx, u, 64);
    L[u + 1] = L[u] + (__shfl(ex, u, 64) - starts[u]);
  }
  int deg = L[NCOH];
  float a[6] = {0.f, 0.f, 0.f, 0.f, 0.f, 0.f};
  for (int c0 = 0; c0 < deg; c0 += 64) {
    int p = c0 + lane;
    if (p < deg) {
      int u = 0;
#pragma unroll
      for (int t = 1; t < NCOH; ++t) u += (p >= L[t]);
      int s = csr8[starts[u] + (p - L[u])];  // lane-owned edge; one preload
#pragma unroll
      for (int j = 0; j < 6; ++j) a[j] += xs[s * 6 + j];  // 6 independent loads
    }
  }
  if (lane == 0) {
#pragma unroll
    for (int j = 0; j < 6; ++j) a[j] += xs[v * 6 + j];  // self-loop
  }
#pragma unroll
  for (int off = 32; off >= 1; off >>= 1) {
#pragma unroll
    for (int j = 0; j < 6; ++j) a[j] += __shfl_xor(a[j], off, 64);
  }
  float dv = dinv[v];
#pragma unroll
  for (int j = 0; j < 6; ++j) a[j] *= dv;
  int f0 = lane, f1 = lane + 64;
  float o0 = b1[f0], o1 = b1[f1];
#pragma unroll
  for (int j = 0; j < 6; ++j) {
    o0 = fmaf(a[j], W1[j * HDIM + f0], o0);
    o1 = fmaf(a[j], W1[j * HDIM + f1], o1);
  }
  float s = o0 + o1, q = o0 * o0 + o1 * o1;
#pragma unroll
  for (int off = 32; off >= 1; off >>= 1) {
    s += __shfl_xor(s, off, 64);
    q += __shfl_xor(q, off, 64);
  }
  float m = s * (1.0f / HDIM);
  float var = fmaxf(q * (1.0f / HDIM) - m * m, 0.f);
  float rs = rsqrtf(var + LN_EPS);
  float y0 = fmaxf(fmaf((o0 - m) * rs, gam[f0], bet[f0]), 0.f);
  float y1 = fmaxf(fmaf((o1 - m) * rs, gam[f1], bet[f1]), 0.f);
  hout[v * HDIM + f0] = __float2half(y0 * dv);  // store h' = dinv*h
  hout[v * HDIM + f1] = __float2half(y1 * dv);
}

// ---------------- Aggregation: one wave/node; index preload + shfl bcast, 16-deep ----------

__global__ __launch_bounds__(256) void agg_kernel(
    const __half* __restrict__ hin, const int* __restrict__ rowptr8,
    const int* __restrict__ csr8, const float* __restrict__ dinv,
    __half* __restrict__ agg, int n) {
  int v = blockIdx.x * 4 + (threadIdx.x >> 6);
  if (v >= n) return;
  int lane = threadIdx.x & 63;
  const __half2* h2 = (const __half2*)hin;
  float2 hf = __half22float2(h2[v * 64 + lane]);
  float ax = hf.x, ay = hf.y;  // self-loop
  int sx = 0, ex = 0;
  if (lane < NCOH) {
    sx = rowptr8[lane * n + v];
    ex = rowptr8[lane * n + v + 1];
  }
  int starts[NCOH], L[NCOH + 1];
  L[0] = 0;
#pragma unroll
  for (int u = 0; u < NCOH; ++u) {
    starts[u] = __shfl(sx, u, 64);
    L[u + 1] = L[u] + (__shfl(ex, u, 64) - starts[u]);
  }
  int deg = L[NCOH];
  for (int c0 = 0; c0 < deg; c0 += 64) {
    int p = c0 + lane;
    int myidx = 0;
    if (p < deg) {
      int u = 0;
#pragma unroll
      for (int t = 1; t < NCOH; ++t) u += (p >= L[t]);
      myidx = csr8[starts[u] + (p - L[u])];  // one lane-parallel load for 64 indices
    }
    int cnt = min(deg - c0, 64);
    int j = 0;
    // 16 independent 256B row-gathers in flight.
    for (; j + 16 <= cnt; j += 16) {
      float2 g[16];
#pragma unroll
      for (int u = 0; u < 16; ++u) {
        int s = __shfl(myidx, j + u, 64);
        g[u] = __half22float2(h2[s * 64 + lane]);
      }
#pragma unroll
      for (int u = 0; u < 16; ++u) {
        ax += g[u].x;
        ay += g[u].y;
      }
    }
    for (; j + 8 <= cnt; j += 8) {
      float2 g[8];
#pragma unroll
      for (int u = 0; u < 8; ++u) {
        int s = __shfl(myidx, j + u, 64);
        g[u] = __half22float2(h2[s * 64 + lane]);
      }
#pragma unroll
      for (int u = 0; u < 8; ++u) {
        ax += g[u].x;
        ay += g[u].y;
      }
    }
    for (; j < cnt; ++j) {
      int s = __shfl(myidx, j, 64);
      float2 f = __half22float2(h2[s * 64 + lane]);
      ax += f.x;
      ay += f.y;
    }
  }
  float dv = dinv[v];
  ((__half2*)agg)[v * 64 + lane] = __floats2half2_rn(ax * dv, ay * dv);
}

// ---------------- MFMA GEMM + LN (+ReLU -> fp16 h' | + MFMA head -> out) ----------------

__global__ __launch_bounds__(256) void mfma_gemm_kernel(
    const __half* __restrict__ aggh, const __half* __restrict__ Wt,
    const float* __restrict__ bias, const float* __restrict__ gam,
    const float* __restrict__ bet, const float* __restrict__ dinv,
    __half* __restrict__ hout,
    const __half* __restrict__ rW1t, const float* __restrict__ rb1,
    const float* __restrict__ rW2, const float* __restrict__ rb2,
    float* __restrict__ out, int n, int mode) {
  __shared__ __align__(16) __half smem[128 * 136];  // Wt staged; later aliased as tile
  int tid = threadIdx.x;
  int v0 = blockIdx.x * 64;
  int lane = tid & 63;
  int wv = tid >> 6;
  int m = lane & 15;
  int q = lane >> 4;

#pragma unroll
  for (int i = 0; i < 8; ++i) {
    int u = tid + i * 256;
    int row = u >> 4, seg = u & 15;
    *(uint4*)&smem[row * 136 + seg * 8] = *(const uint4*)&Wt[row * 128 + seg * 8];
  }

  int row = v0 + wv * 16 + m;
  int rowc = row < n ? row : n - 1;
  const __half* abase = aggh + (size_t)rowc * 128 + q * 8;
  half8 afrag[4];
#pragma unroll
  for (int kt = 0; kt < 4; ++kt) afrag[kt] = *(const half8*)(abase + kt * 32);

  __syncthreads();

  f32x4 acc[8];
#pragma unroll
  for (int c = 0; c < 8; ++c) acc[c] = (f32x4){0.f, 0.f, 0.f, 0.f};
#pragma unroll
  for (int kt = 0; kt < 4; ++kt) {
#pragma unroll
    for (int c = 0; c < 8; ++c) {
      half8 b = *(const half8*)&smem[(c * 16 + m) * 136 + kt * 32 + q * 8];
      acc[c] = __builtin_amdgcn_mfma_f32_16x16x32_f16(afrag[kt], b, acc[c], 0, 0, 0);
    }
  }

#pragma unroll
  for (int c = 0; c < 8; ++c) {
    float bcol = bias[c * 16 + m];
#pragma unroll
    for (int r = 0; r < 4; ++r) acc[c][r] += bcol;
  }
  float mean[4], rstd[4], dvr[4];
#pragma unroll
  for (int r = 0; r < 4; ++r) {
    float s = 0.f, q2 = 0.f;
#pragma unroll
    for (int c = 0; c < 8; ++c) {
      float vv = acc[c][r];
      s += vv;
      q2 += vv * vv;
    }
#pragma unroll
    for (int off = 8; off >= 1; off >>= 1) {
      s += __shfl_xor(s, off, 16);
      q2 += __shfl_xor(q2, off, 16);
    }
    float mu = s * (1.f / HDIM);
    float var = fmaxf(q2 * (1.f / HDIM) - mu * mu, 0.f);
    mean[r] = mu;
    rstd[r] = rsqrtf(var + LN_EPS);
    int vr = v0 + wv * 16 + q * 4 + r;
    dvr[r] = (mode == 1 && vr < n) ? dinv[vr] : 1.f;
  }

  __syncthreads();
  __half* tile = smem;  // 64 x 136
#pragma unroll
  for (int c = 0; c < 8; ++c) {
    float g = gam[c * 16 + m], bb = bet[c * 16 + m];
#pragma unroll
    for (int r = 0; r < 4; ++r) {
      float y = fmaf((acc[c][r] - mean[r]) * rstd[r], g, bb);
      if (mode == 1) y = fmaxf(y, 0.f) * dvr[r];
      tile[(wv * 16 + q * 4 + r) * 136 + c * 16 + m] = __float2half(y);
    }
  }
  __syncthreads();

  if (mode == 1) {
#pragma unroll
    for (int i = 0; i < 4; ++i) {
      int u = tid + i * 256;
      int r = u >> 4, seg = u & 15;
      int v = v0 + r;
      if (v < n) *(uint4*)&hout[(size_t)v * 128 + seg * 8] = *(const uint4*)&tile[r * 136 + seg * 8];
    }
    return;
  }

  f32x4 hacc[4];
#pragma unroll
  for (int c = 0; c < 4; ++c) hacc[c] = (f32x4){0.f, 0.f, 0.f, 0.f};
#pragma unroll
  for (int kt = 0; kt < 4; ++kt) {
    half8 a = *(const half8*)&tile[(wv * 16 + m) * 136 + kt * 32 + q * 8];
#pragma unroll
    for (int c = 0; c < 4; ++c) {
      half8 b = *(const half8*)&rW1t[(c * 16 + m) * 128 + kt * 32 + q * 8];
      hacc[c] = __builtin_amdgcn_mfma_f32_16x16x32_f16(a, b, hacc[c], 0, 0, 0);
    }
  }
  float p[4] = {0.f, 0.f, 0.f, 0.f};
#pragma unroll
  for (int c = 0; c < 4; ++c) {
    float rb = rb1[c * 16 + m], w2 = rW2[c * 16 + m];
#pragma unroll
    for (int r = 0; r < 4; ++r) {
      float hv = fmaxf(hacc[c][r] + rb, 0.f);
      p[r] = fmaf(hv, w2, p[r]);
    }
  }
#pragma unroll
  for (int r = 0; r < 4; ++r) {
#pragma unroll
    for (int off = 8; off >= 1; off >>= 1) p[r] += __shfl_xor(p[r], off, 16);
  }
  if (m == 0) {
    float rb2v = rb2[0];
#pragma unroll
    for (int r = 0; r < 4; ++r) {
      int v = v0 + wv * 16 + q * 4 + r;
      if (v < n) out[v] = 1.f / (1.f + expf(-(p[r] + rb2v)));
    }
  }
}

// ---------------- Launch ----------------

extern "C" void kernel_launch(void* const* d_in, const int* in_sizes, int n_in,
                              void* d_out, int out_size, void* d_ws, size_t ws_size,
                              hipStream_t stream) {
  const float* x   = (const float*)d_in[0];
  const int*  eidx = (const int*)d_in[1];
  const float* W1  = (const float*)d_in[2];
  const float* b1  = (const float*)d_in[3];
  const float* W2  = (const float*)d_in[4];
  const float* b2  = (const float*)d_in[5];
  const float* W3  = (const float*)d_in[6];
  const float* b3  = (const float*)d_in[7];
  const float* g1  = (const float*)d_in[8];
  const float* be1 = (const float*)d_in[9];
  const float* g2  = (const float*)d_in[10];
  const float* be2 = (const float*)d_in[11];
  const float* g3  = (const float*)d_in[12];
  const float* be3 = (const float*)d_in[13];
  const float* rW1 = (const float*)d_in[14];
  const float* rb1 = (const float*)d_in[15];
  const float* rW2 = (const float*)d_in[16];
  const float* rb2 = (const float*)d_in[17];

  int N = in_sizes[0] / 6;
  int E = in_sizes[1] / 2;
  const int* srcp = eidx;
  const int* dstp = eidx + E;
  float* out = (float*)d_out;

  char* p = (char*)d_ws;
  auto alloc = [&](size_t bytes) -> void* {
    void* r = (void*)p;
    p += (bytes + 255) & ~(size_t)255;
    return r;
  };
  int*    counts8  = (int*)alloc((size_t)NCOH * N * 4);
  int*    rowptr8  = (int*)alloc(((size_t)NCOH * N + 1) * 4);
  int*    cursor8  = (int*)alloc((size_t)NCOH * N * 4);
  float*  dinvp    = (float*)alloc((size_t)N * 4);
  int*    blocksum = (int*)alloc((size_t)1024 * 4);
  int*    csr8     = (int*)alloc((size_t)E * 4);
  float*  xs       = (float*)alloc((size_t)N * 6 * 4);
  __half* h16_a    = (__half*)alloc((size_t)N * HDIM * 2);
  __half* h16_b    = (__half*)alloc((size_t)N * HDIM * 2);
  __half* aggbuf   = (__half*)alloc((size_t)N * HDIM * 2);
  __half* w2t      = (__half*)alloc((size_t)HDIM * HDIM * 2);
  __half* w3t      = (__half*)alloc((size_t)HDIM * HDIM * 2);
  __half* rw1t     = (__half*)alloc((size_t)64 * HDIM * 2);

  int M8 = NCOH * N;
  int nscan8 = (M8 + 2047) / 2048;  // 196 blocks for N=50k

  hipMemsetAsync(counts8, 0, (size_t)M8 * 4, stream);
  count_kernel<<<(E + 255) / 256, 256, 0, stream>>>(dstp, counts8, E, N);
  dinv_kernel<<<(N + 255) / 256, 256, 0, stream>>>(counts8, dinvp, N);
  scan_sum_kernel<<<nscan8, 256, 0, stream>>>(counts8, blocksum, M8);
  scan2_kernel<<<1, 256, 0, stream>>>(blocksum, nscan8);
  scan_emit_kernel<<<nscan8, 256, 0, stream>>>(counts8, blocksum, rowptr8, cursor8, M8, nscan8);
  fill_kernel<<<(E + 255) / 256, 256, 0, stream>>>(srcp, dstp, cursor8, csr8, E, N);
  prep_kernel<<<(N * 6 + 40960 + 255) / 256, 256, 0, stream>>>(x, dinvp, xs, W2, W3, rW1,
                                                               w2t, w3t, rw1t, N);

  int nw = (N + 3) / 4;
  int nb = (N + 63) / 64;
  layer1_kernel<<<nw, 256, 0, stream>>>(xs, W1, b1, g1, be1, rowptr8, csr8, dinvp, h16_a, N);
  agg_kernel<<<nw, 256, 0, stream>>>(h16_a, rowptr8, csr8, dinvp, aggbuf, N);
  mfma_gemm_kernel<<<nb, 256, 0, stream>>>(aggbuf, w2t, b2, g2, be2, dinvp, h16_b,
                                           rw1t, rb1, rW2, rb2, out, N, 1);
  agg_kernel<<<nw, 256, 0, stream>>>(h16_b, rowptr8, csr8, dinvp, aggbuf, N);
  mfma_gemm_kernel<<<nb, 256, 0, stream>>>(aggbuf, w3t, b3, g3, be3, dinvp, h16_b,
                                           rw1t, rb1, rW2, rb2, out, N, 2);
}

// Round 12
// 302.623 us; speedup vs baseline: 1.3537x; 1.0727x over previous
//
#include <hip/hip_runtime.h>
#include <hip/hip_fp16.h>
#include <math.h>

#define HDIM 128
#define LN_EPS 1e-5f
#define NCOH 8  // XCD cohorts (blockIdx % 8 ~ XCD round-robin heuristic; perf-only)

typedef _Float16 half8 __attribute__((ext_vector_type(8)));
typedef float f32x4 __attribute__((ext_vector_type(4)));

// h'[v] = dinv[v]*h[v]; agg[v] = dinv[v]*(sum_{s in N(v)} h'[s] + h'[v]).
// CSR is cohort-sharded x-major (kills fill write-amplification). agg: 2 nodes
// per wave, 8B/lane uint2 gathers, 16-deep pipeline -> 32 rows in flight/wave.

// ---------------- CSR build ----------------

__global__ void count_kernel(const int* __restrict__ dst, int* __restrict__ counts8,
                             int E, int n) {
  int e = blockIdx.x * blockDim.x + threadIdx.x;
  int x = blockIdx.x & (NCOH - 1);
  if (e < E) atomicAdd(&counts8[x * n + dst[e]], 1);
}

__global__ void dinv_kernel(const int* __restrict__ counts8, float* __restrict__ dinv, int n) {
  int i = blockIdx.x * 256 + threadIdx.x;
  if (i < n) {
    int s = 0;
#pragma unroll
    for (int x = 0; x < NCOH; ++x) s += counts8[x * n + i];
    dinv[i] = rsqrtf((float)(s + 1));  // +1 self-loop
  }
}

__global__ __launch_bounds__(256) void scan_sum_kernel(const int* __restrict__ in,
                                                       int* __restrict__ blocksum, int n) {
  int base = blockIdx.x * 2048;
  int tid = threadIdx.x;
  int sum = 0;
#pragma unroll
  for (int j = 0; j < 8; ++j) {
    int i = base + tid * 8 + j;
    if (i < n) sum += in[i];
  }
#pragma unroll
  for (int off = 32; off >= 1; off >>= 1) sum += __shfl_xor(sum, off, 64);
  __shared__ int wsum[4];
  if ((tid & 63) == 0) wsum[tid >> 6] = sum;
  __syncthreads();
  if (tid == 0) blocksum[blockIdx.x] = wsum[0] + wsum[1] + wsum[2] + wsum[3];
}

__global__ __launch_bounds__(256) void scan2_kernel(int* __restrict__ blocksum, int nblk) {
  __shared__ int sh[256];
  int tid = threadIdx.x;
  sh[tid] = (tid < nblk) ? blocksum[tid] : 0;
  __syncthreads();
  for (int off = 1; off < 256; off <<= 1) {
    int t = (tid >= off) ? sh[tid - off] : 0;
    __syncthreads();
    sh[tid] += t;
    __syncthreads();
  }
  if (tid < nblk) blocksum[tid] = sh[tid];  // inclusive
}

__global__ __launch_bounds__(256) void scan_emit_kernel(const int* __restrict__ in,
                                                        const int* __restrict__ blocksum,
                                                        int* __restrict__ rowptr8,
                                                        int* __restrict__ cursor8, int n, int nblk) {
  int base = blockIdx.x * 2048;
  int tid = threadIdx.x;
  int c[8];
  int s = 0;
#pragma unroll
  for (int j = 0; j < 8; ++j) {
    int i = base + tid * 8 + j;
    c[j] = (i < n) ? in[i] : 0;
    s += c[j];
  }
  int lane = tid & 63, wid = tid >> 6;
  int incl = s;
#pragma unroll
  for (int off = 1; off < 64; off <<= 1) {
    int t = __shfl_up(incl, off, 64);
    if (lane >= off) incl += t;
  }
  __shared__ int wsum[4];
  if (lane == 63) wsum[wid] = incl;
  __syncthreads();
  int woff = 0;
  for (int w = 0; w < wid; ++w) woff += wsum[w];
  int p = (blockIdx.x == 0 ? 0 : blocksum[blockIdx.x - 1]) + woff + (incl - s);
#pragma unroll
  for (int j = 0; j < 8; ++j) {
    int i = base + tid * 8 + j;
    if (i < n) {
      rowptr8[i] = p;
      cursor8[i] = p;
    }
    p += c[j];
  }
  if (blockIdx.x == nblk - 1 && tid == 255) rowptr8[n] = blocksum[nblk - 1];
}

__global__ void fill_kernel(const int* __restrict__ src, const int* __restrict__ dst,
                            int* __restrict__ cursor8, int* __restrict__ csr8, int E, int n) {
  int e = blockIdx.x * blockDim.x + threadIdx.x;
  int x = blockIdx.x & (NCOH - 1);
  if (e < E) {
    int pos = atomicAdd(&cursor8[x * n + dst[e]], 1);
    csr8[pos] = src[e];  // cohort-owned contiguous region -> XCD-local L2 lines
  }
}

// ---------------- Prep: xs (stride 8) = dinv*x ; fp16-transposed weights ----------------

__global__ void prep_kernel(const float* __restrict__ x, const float* __restrict__ dinv,
                            float* __restrict__ xs, const float* __restrict__ W2,
                            const float* __restrict__ W3, const float* __restrict__ rW1,
                            __half* __restrict__ w2t, __half* __restrict__ w3t,
                            __half* __restrict__ rw1t, int n) {
  int idx = blockIdx.x * 256 + threadIdx.x;
  int nx = n * 8;
  if (idx < nx) {
    int vv = idx >> 3, j = idx & 7;
    xs[idx] = (j < 6) ? x[vv * 6 + j] * dinv[vv] : 0.f;
    return;
  }
  int i = idx - nx;
  if (i < 16384) {
    int nn = i >> 7, k = i & 127;
    w2t[i] = __float2half(W2[k * 128 + nn]);
  } else if (i < 32768) {
    int j = i - 16384;
    int nn = j >> 7, k = j & 127;
    w3t[j] = __float2half(W3[k * 128 + nn]);
  } else if (i < 40960) {
    int j = i - 32768;
    int nn = j >> 7, k = j & 127;
    rw1t[j] = __float2half(rW1[k * 64 + nn]);
  }
}

// ---------------- Layer 1: one wave/node; lane-owned edges, 2x float4 loads ----------

__global__ __launch_bounds__(256) void layer1_kernel(
    const float* __restrict__ xs, const float* __restrict__ W1,
    const float* __restrict__ b1, const float* __restrict__ gam,
    const float* __restrict__ bet, const int* __restrict__ rowptr8,
    const int* __restrict__ csr8, const float* __restrict__ dinv,
    __half* __restrict__ hout, int n) {
  int v = blockIdx.x * 4 + (threadIdx.x >> 6);
  if (v >= n) return;
  int lane = threadIdx.x & 63;
  int sx = 0, ex = 0;
  if (lane < NCOH) {
    sx = rowptr8[lane * n + v];
    ex = rowptr8[lane * n + v + 1];
  }
  int starts[NCOH], L[NCOH + 1];
  L[0] = 0;
#pragma unroll
  for (int u = 0; u < NCOH; ++u) {
    starts[u] = __shfl(sx, u, 64);
    L[u + 1] = L[u] + (__shfl(ex, u, 64) - starts[u]);
  }
  int deg = L[NCOH];
  float a[6] = {0.f, 0.f, 0.f, 0.f, 0.f, 0.f};
  for (int c0 = 0; c0 < deg; c0 += 64) {
    int p = c0 + lane;
    if (p < deg) {
      int u = 0;
#pragma unroll
      for (int t = 1; t < NCOH; ++t) u += (p >= L[t]);
      int s = csr8[starts[u] + (p - L[u])];  // lane-owned edge
      float4 x0 = *(const float4*)&xs[s * 8];
      float4 x1 = *(const float4*)&xs[s * 8 + 4];
      a[0] += x0.x; a[1] += x0.y; a[2] += x0.z;
      a[3] += x0.w; a[4] += x1.x; a[5] += x1.y;
    }
  }
  if (lane == 0) {
#pragma unroll
    for (int j = 0; j < 6; ++j) a[j] += xs[v * 8 + j];  // self-loop
  }
#pragma unroll
  for (int off = 32; off >= 1; off >>= 1) {
#pragma unroll
    for (int j = 0; j < 6; ++j) a[j] += __shfl_xor(a[j], off, 64);
  }
  float dv = dinv[v];
#pragma unroll
  for (int j = 0; j < 6; ++j) a[j] *= dv;
  int f0 = lane, f1 = lane + 64;
  float o0 = b1[f0], o1 = b1[f1];
#pragma unroll
  for (int j = 0; j < 6; ++j) {
    o0 = fmaf(a[j], W1[j * HDIM + f0], o0);
    o1 = fmaf(a[j], W1[j * HDIM + f1], o1);
  }
  float s = o0 + o1, q = o0 * o0 + o1 * o1;
#pragma unroll
  for (int off = 32; off >= 1; off >>= 1) {
    s += __shfl_xor(s, off, 64);
    q += __shfl_xor(q, off, 64);
  }
  float m = s * (1.0f / HDIM);
  float var = fmaxf(q * (1.0f / HDIM) - m * m, 0.f);
  float rs = rsqrtf(var + LN_EPS);
  float y0 = fmaxf(fmaf((o0 - m) * rs, gam[f0], bet[f0]), 0.f);
  float y1 = fmaxf(fmaf((o1 - m) * rs, gam[f1], bet[f1]), 0.f);
  hout[v * HDIM + f0] = __float2half(y0 * dv);  // store h' = dinv*h
  hout[v * HDIM + f1] = __float2half(y1 * dv);
}

// ---------------- Aggregation: 2 nodes/wave, uint2 (8B)/lane, 16-deep => 32 rows in flight ----

__device__ __forceinline__ void add4(float& a0, float& a1, float& a2, float& a3, uint2 g) {
  __half2 lo = *(__half2*)&g.x;
  __half2 hi = *(__half2*)&g.y;
  float2 f0 = __half22float2(lo);
  float2 f1 = __half22float2(hi);
  a0 += f0.x; a1 += f0.y; a2 += f1.x; a3 += f1.y;
}

__global__ __launch_bounds__(256) void agg_kernel(
    const __half* __restrict__ hin, const int* __restrict__ rowptr8,
    const int* __restrict__ csr8, const float* __restrict__ dinv,
    __half* __restrict__ agg, int n) {
  int lane = threadIdx.x & 63;
  int wave = threadIdx.x >> 6;
  int hl = lane & 31;                              // lane within half-wave
  int v = blockIdx.x * 8 + wave * 2 + (lane >> 5); // 2 nodes per wave
  int vc = v < n ? v : n - 1;
  const uint2* h4 = (const uint2*)hin;  // 8B units; row = 32 units (256B)
  uint2 self = h4[(size_t)vc * 32 + hl];
  float a0 = 0.f, a1 = 0.f, a2 = 0.f, a3 = 0.f;
  add4(a0, a1, a2, a3, self);  // self-loop

  int sx = 0, ex = 0;
  if (hl < NCOH) {
    sx = rowptr8[hl * n + vc];
    ex = rowptr8[hl * n + vc + 1];
  }
  int starts[NCOH], L[NCOH + 1];
  L[0] = 0;
#pragma unroll
  for (int u = 0; u < NCOH; ++u) {
    starts[u] = __shfl(sx, u, 32);  // within own half
    L[u + 1] = L[u] + (__shfl(ex, u, 32) - starts[u]);
  }
  int deg = L[NCOH];
  for (int c0 = 0; c0 < deg; c0 += 32) {
    int p = c0 + hl;
    int myidx = 0;
    if (p < deg) {
      int u = 0;
#pragma unroll
      for (int t = 1; t < NCOH; ++t) u += (p >= L[t]);
      myidx = csr8[starts[u] + (p - L[u])];  // lane-parallel index preload
    }
    int cnt = min(deg - c0, 32);
    for (int j = 0; j < cnt; j += 16) {
      uint2 g[16];
#pragma unroll
      for (int u = 0; u < 16; ++u) {
        int s = __shfl(myidx, min(j + u, cnt - 1), 32);  // clamp: loads unconditional
        g[u] = h4[(size_t)s * 32 + hl];
      }
#pragma unroll
      for (int u = 0; u < 16; ++u) {
        if (j + u < cnt) add4(a0, a1, a2, a3, g[u]);  // masked add
      }
    }
  }
  float dv = dinv[vc];
  if (v < n) {
    uint2 outp;
    __half2 lo = __floats2half2_rn(a0 * dv, a1 * dv);
    __half2 hi = __floats2half2_rn(a2 * dv, a3 * dv);
    outp.x = *(unsigned*)&lo;
    outp.y = *(unsigned*)&hi;
    ((uint2*)agg)[(size_t)v * 32 + hl] = outp;
  }
}

// ---------------- MFMA GEMM + LN (+ReLU -> fp16 h' | + MFMA head -> out) ----------------

__global__ __launch_bounds__(256) void mfma_gemm_kernel(
    const __half* __restrict__ aggh, const __half* __restrict__ Wt,
    const float* __restrict__ bias, const float* __restrict__ gam,
    const float* __restrict__ bet, const float* __restrict__ dinv,
    __half* __restrict__ hout,
    const __half* __restrict__ rW1t, const float* __restrict__ rb1,
    const float* __restrict__ rW2, const float* __restrict__ rb2,
    float* __restrict__ out, int n, int mode) {
  __shared__ __align__(16) __half smem[128 * 136];  // Wt staged; later aliased as tile
  int tid = threadIdx.x;
  int v0 = blockIdx.x * 64;
  int lane = tid & 63;
  int wv = tid >> 6;
  int m = lane & 15;
  int q = lane >> 4;

#pragma unroll
  for (int i = 0; i < 8; ++i) {
    int u = tid + i * 256;
    int row = u >> 4, seg = u & 15;
    *(uint4*)&smem[row * 136 + seg * 8] = *(const uint4*)&Wt[row * 128 + seg * 8];
  }

  int row = v0 + wv * 16 + m;
  int rowc = row < n ? row : n - 1;
  const __half* abase = aggh + (size_t)rowc * 128 + q * 8;
  half8 afrag[4];
#pragma unroll
  for (int kt = 0; kt < 4; ++kt) afrag[kt] = *(const half8*)(abase + kt * 32);

  __syncthreads();

  f32x4 acc[8];
#pragma unroll
  for (int c = 0; c < 8; ++c) acc[c] = (f32x4){0.f, 0.f, 0.f, 0.f};
#pragma unroll
  for (int kt = 0; kt < 4; ++kt) {
#pragma unroll
    for (int c = 0; c < 8; ++c) {
      half8 b = *(const half8*)&smem[(c * 16 + m) * 136 + kt * 32 + q * 8];
      acc[c] = __builtin_amdgcn_mfma_f32_16x16x32_f16(afrag[kt], b, acc[c], 0, 0, 0);
    }
  }

#pragma unroll
  for (int c = 0; c < 8; ++c) {
    float bcol = bias[c * 16 + m];
#pragma unroll
    for (int r = 0; r < 4; ++r) acc[c][r] += bcol;
  }
  float mean[4], rstd[4], dvr[4];
#pragma unroll
  for (int r = 0; r < 4; ++r) {
    float s = 0.f, q2 = 0.f;
#pragma unroll
    for (int c = 0; c < 8; ++c) {
      float vv = acc[c][r];
      s += vv;
      q2 += vv * vv;
    }
#pragma unroll
    for (int off = 8; off >= 1; off >>= 1) {
      s += __shfl_xor(s, off, 16);
      q2 += __shfl_xor(q2, off, 16);
    }
    float mu = s * (1.f / HDIM);
    float var = fmaxf(q2 * (1.f / HDIM) - mu * mu, 0.f);
    mean[r] = mu;
    rstd[r] = rsqrtf(var + LN_EPS);
    int vr = v0 + wv * 16 + q * 4 + r;
    dvr[r] = (mode == 1 && vr < n) ? dinv[vr] : 1.f;
  }

  __syncthreads();
  __half* tile = smem;  // 64 x 136
#pragma unroll
  for (int c = 0; c < 8; ++c) {
    float g = gam[c * 16 + m], bb = bet[c * 16 + m];
#pragma unroll
    for (int r = 0; r < 4; ++r) {
      float y = fmaf((acc[c][r] - mean[r]) * rstd[r], g, bb);
      if (mode == 1) y = fmaxf(y, 0.f) * dvr[r];
      tile[(wv * 16 + q * 4 + r) * 136 + c * 16 + m] = __float2half(y);
    }
  }
  __syncthreads();

  if (mode == 1) {
#pragma unroll
    for (int i = 0; i < 4; ++i) {
      int u = tid + i * 256;
      int r = u >> 4, seg = u & 15;
      int v = v0 + r;
      if (v < n) *(uint4*)&hout[(size_t)v * 128 + seg * 8] = *(const uint4*)&tile[r * 136 + seg * 8];
    }
    return;
  }

  f32x4 hacc[4];
#pragma unroll
  for (int c = 0; c < 4; ++c) hacc[c] = (f32x4){0.f, 0.f, 0.f, 0.f};
#pragma unroll
  for (int kt = 0; kt < 4; ++kt) {
    half8 a = *(const half8*)&tile[(wv * 16 + m) * 136 + kt * 32 + q * 8];
#pragma unroll
    for (int c = 0; c < 4; ++c) {
      half8 b = *(const half8*)&rW1t[(c * 16 + m) * 128 + kt * 32 + q * 8];
      hacc[c] = __builtin_amdgcn_mfma_f32_16x16x32_f16(a, b, hacc[c], 0, 0, 0);
    }
  }
  float p[4] = {0.f, 0.f, 0.f, 0.f};
#pragma unroll
  for (int c = 0; c < 4; ++c) {
    float rb = rb1[c * 16 + m], w2 = rW2[c * 16 + m];
#pragma unroll
    for (int r = 0; r < 4; ++r) {
      float hv = fmaxf(hacc[c][r] + rb, 0.f);
      p[r] = fmaf(hv, w2, p[r]);
    }
  }
#pragma unroll
  for (int r = 0; r < 4; ++r) {
#pragma unroll
    for (int off = 8; off >= 1; off >>= 1) p[r] += __shfl_xor(p[r], off, 16);
  }
  if (m == 0) {
    float rb2v = rb2[0];
#pragma unroll
    for (int r = 0; r < 4; ++r) {
      int v = v0 + wv * 16 + q * 4 + r;
      if (v < n) out[v] = 1.f / (1.f + expf(-(p[r] + rb2v)));
    }
  }
}

// ---------------- Launch ----------------

extern "C" void kernel_launch(void* const* d_in, const int* in_sizes, int n_in,
                              void* d_out, int out_size, void* d_ws, size_t ws_size,
                              hipStream_t stream) {
  const float* x   = (const float*)d_in[0];
  const int*  eidx = (const int*)d_in[1];
  const float* W1  = (const float*)d_in[2];
  const float* b1  = (const float*)d_in[3];
  const float* W2  = (const float*)d_in[4];
  const float* b2  = (const float*)d_in[5];
  const float* W3  = (const float*)d_in[6];
  const float* b3  = (const float*)d_in[7];
  const float* g1  = (const float*)d_in[8];
  const float* be1 = (const float*)d_in[9];
  const float* g2  = (const float*)d_in[10];
  const float* be2 = (const float*)d_in[11];
  const float* g3  = (const float*)d_in[12];
  const float* be3 = (const float*)d_in[13];
  const float* rW1 = (const float*)d_in[14];
  const float* rb1 = (const float*)d_in[15];
  const float* rW2 = (const float*)d_in[16];
  const float* rb2 = (const float*)d_in[17];

  int N = in_sizes[0] / 6;
  int E = in_sizes[1] / 2;
  const int* srcp = eidx;
  const int* dstp = eidx + E;
  float* out = (float*)d_out;

  char* p = (char*)d_ws;
  auto alloc = [&](size_t bytes) -> void* {
    void* r = (void*)p;
    p += (bytes + 255) & ~(size_t)255;
    return r;
  };
  int*    counts8  = (int*)alloc((size_t)NCOH * N * 4);
  int*    rowptr8  = (int*)alloc(((size_t)NCOH * N + 1) * 4);
  int*    cursor8  = (int*)alloc((size_t)NCOH * N * 4);
  float*  dinvp    = (float*)alloc((size_t)N * 4);
  int*    blocksum = (int*)alloc((size_t)1024 * 4);
  int*    csr8     = (int*)alloc((size_t)E * 4);
  float*  xs       = (float*)alloc((size_t)N * 8 * 4);
  __half* h16_a    = (__half*)alloc((size_t)N * HDIM * 2);
  __half* h16_b    = (__half*)alloc((size_t)N * HDIM * 2);
  __half* aggbuf   = (__half*)alloc((size_t)N * HDIM * 2);
  __half* w2t      = (__half*)alloc((size_t)HDIM * HDIM * 2);
  __half* w3t      = (__half*)alloc((size_t)HDIM * HDIM * 2);
  __half* rw1t     = (__half*)alloc((size_t)64 * HDIM * 2);

  int M8 = NCOH * N;
  int nscan8 = (M8 + 2047) / 2048;

  hipMemsetAsync(counts8, 0, (size_t)M8 * 4, stream);
  count_kernel<<<(E + 255) / 256, 256, 0, stream>>>(dstp, counts8, E, N);
  dinv_kernel<<<(N + 255) / 256, 256, 0, stream>>>(counts8, dinvp, N);
  scan_sum_kernel<<<nscan8, 256, 0, stream>>>(counts8, blocksum, M8);
  scan2_kernel<<<1, 256, 0, stream>>>(blocksum, nscan8);
  scan_emit_kernel<<<nscan8, 256, 0, stream>>>(counts8, blocksum, rowptr8, cursor8, M8, nscan8);
  fill_kernel<<<(E + 255) / 256, 256, 0, stream>>>(srcp, dstp, cursor8, csr8, E, N);
  prep_kernel<<<(N * 8 + 40960 + 255) / 256, 256, 0, stream>>>(x, dinvp, xs, W2, W3, rW1,
                                                               w2t, w3t, rw1t, N);

  int nw = (N + 3) / 4;    // layer1: one wave per node
  int nw2 = (N + 7) / 8;   // agg: two nodes per wave
  int nb = (N + 63) / 64;  // gemm: 64 rows per block
  layer1_kernel<<<nw, 256, 0, stream>>>(xs, W1, b1, g1, be1, rowptr8, csr8, dinvp, h16_a, N);
  agg_kernel<<<nw2, 256, 0, stream>>>(h16_a, rowptr8, csr8, dinvp, aggbuf, N);
  mfma_gemm_kernel<<<nb, 256, 0, stream>>>(aggbuf, w2t, b2, g2, be2, dinvp, h16_b,
                                           rw1t, rb1, rW2, rb2, out, N, 1);
  agg_kernel<<<nw2, 256, 0, stream>>>(h16_b, rowptr8, csr8, dinvp, aggbuf, N);
  mfma_gemm_kernel<<<nb, 256, 0, stream>>>(aggbuf, w3t, b3, g3, be3, dinvp, h16_b,
                                           rw1t, rb1, rW2, rb2, out, N, 2);
}